// Round 1
// baseline (3070.466 us; speedup 1.0000x reference)
//
#include <hip/hip_runtime.h>
#include <hip/hip_bf16.h>

#define WAVE 64
#define WPB 4               // waves per block
#define EPW 4               // items (edges/nodes) per wave
#define BLOCK (WAVE * WPB)

__device__ __forceinline__ float tanh_fast(float xv) {
    // tanh(x) = 1 - 2/(exp(2x)+1), exp via exp2. Handles +/-inf saturation correctly.
    float t = __builtin_amdgcn_exp2f(xv * 2.8853900817779268f); // 2*log2(e)
    return 1.0f - 2.0f * __builtin_amdgcn_rcpf(t + 1.0f);
}

// ---------------------------------------------------------------------------
// a2s edge MLP: in[13] = [pos_action[src](2), pos_state[dst](2), dis(1), u[src](8)]
// 3-layer MLP (13->64 tanh, 64->64 tanh, 64->64), atomic sum into sum_u[dst].
// ---------------------------------------------------------------------------
__global__ __launch_bounds__(BLOCK) void a2s_kernel(
    const float* __restrict__ pos_state, const float* __restrict__ pos_action,
    const float* __restrict__ u,
    const int* __restrict__ src, const int* __restrict__ dst,
    const float* __restrict__ dis,
    const float* __restrict__ w1, const float* __restrict__ b1,
    const float* __restrict__ w2, const float* __restrict__ b2,
    const float* __restrict__ w3, const float* __restrict__ b3,
    float* __restrict__ sum_u, int E)
{
    __shared__ __align__(16) float w1t[64 * 20];   // K=13 pad 16, stride 20
    __shared__ __align__(16) float w2t[64 * 68];
    __shared__ __align__(16) float w3t[64 * 68];
    __shared__ float b1s[64], b2s[64], b3s[64];
    __shared__ __align__(16) float in_s[WPB][EPW][16];
    __shared__ __align__(16) float act_s[WPB][2][EPW][64];

    int tid = threadIdx.x;
    for (int idx = tid; idx < 13 * 64; idx += BLOCK) { int k = idx >> 6, j = idx & 63; w1t[j * 20 + k] = w1[idx]; }
    for (int idx = tid; idx < 3 * 64; idx += BLOCK) { int j = idx / 3, p = idx % 3; w1t[j * 20 + 13 + p] = 0.f; }
    for (int idx = tid; idx < 64 * 64; idx += BLOCK) { int k = idx >> 6, j = idx & 63; w2t[j * 68 + k] = w2[idx]; w3t[j * 68 + k] = w3[idx]; }
    if (tid < 64) { b1s[tid] = b1[tid]; b2s[tid] = b2[tid]; b3s[tid] = b3[tid]; }
    __syncthreads();

    int wid = tid >> 6, lane = tid & 63;
    int gw = blockIdx.x * WPB + wid;
    int GW = gridDim.x * WPB;
    int tot_groups = (E + EPW - 1) / EPW;
    int iters = (tot_groups + GW - 1) / GW;

    for (int it = 0; it < iters; ++it) {
        int e0 = (it * GW + gw) * EPW;
        int dreg[EPW];
        #pragma unroll
        for (int ei = 0; ei < EPW; ++ei) {
            int e = e0 + ei;
            if (e < E) {
                int s = src[e]; int d = dst[e]; dreg[ei] = d;
                if (lane < 2)       in_s[wid][ei][lane] = pos_action[s * 2 + lane];
                else if (lane < 4)  in_s[wid][ei][lane] = pos_state[d * 2 + lane - 2];
                else if (lane == 4) in_s[wid][ei][4]    = dis[e];
                else if (lane < 13) in_s[wid][ei][lane] = u[s * 8 + lane - 5];
                else if (lane < 16) in_s[wid][ei][lane] = 0.f;
            }
        }
        __syncthreads();

        // layer 1
        float acc[EPW];
        #pragma unroll
        for (int ei = 0; ei < EPW; ++ei) acc[ei] = b1s[lane];
        #pragma unroll
        for (int k = 0; k < 16; k += 4) {
            float4 w = *(const float4*)&w1t[lane * 20 + k];
            #pragma unroll
            for (int ei = 0; ei < EPW; ++ei) {
                float4 a = *(const float4*)&in_s[wid][ei][k];
                acc[ei] += w.x * a.x + w.y * a.y + w.z * a.z + w.w * a.w;
            }
        }
        #pragma unroll
        for (int ei = 0; ei < EPW; ++ei) act_s[wid][0][ei][lane] = tanh_fast(acc[ei]);
        __syncthreads();

        // layer 2
        #pragma unroll
        for (int ei = 0; ei < EPW; ++ei) acc[ei] = b2s[lane];
        for (int k = 0; k < 64; k += 4) {
            float4 w = *(const float4*)&w2t[lane * 68 + k];
            #pragma unroll
            for (int ei = 0; ei < EPW; ++ei) {
                float4 a = *(const float4*)&act_s[wid][0][ei][k];
                acc[ei] += w.x * a.x + w.y * a.y + w.z * a.z + w.w * a.w;
            }
        }
        #pragma unroll
        for (int ei = 0; ei < EPW; ++ei) act_s[wid][1][ei][lane] = tanh_fast(acc[ei]);
        __syncthreads();

        // layer 3 + scatter
        #pragma unroll
        for (int ei = 0; ei < EPW; ++ei) acc[ei] = b3s[lane];
        for (int k = 0; k < 64; k += 4) {
            float4 w = *(const float4*)&w3t[lane * 68 + k];
            #pragma unroll
            for (int ei = 0; ei < EPW; ++ei) {
                float4 a = *(const float4*)&act_s[wid][1][ei][k];
                acc[ei] += w.x * a.x + w.y * a.y + w.z * a.z + w.w * a.w;
            }
        }
        #pragma unroll
        for (int ei = 0; ei < EPW; ++ei) {
            if (e0 + ei < E) atomicAdd(&sum_u[dreg[ei] * 64 + lane], acc[ei]);
        }
        __syncthreads();
    }
}

// ---------------------------------------------------------------------------
// s2s edge MLP: in[77] = [pos_state[src](2), pos_state[dst](2), dis(1), x[src](8), h[src](64)]
// atomic sum into sum_x[dst], deg count.
// ---------------------------------------------------------------------------
__global__ __launch_bounds__(BLOCK) void s2s_kernel(
    const float* __restrict__ pos_state, const float* __restrict__ x,
    const float* __restrict__ h,
    const int* __restrict__ src, const int* __restrict__ dst,
    const float* __restrict__ dis,
    const float* __restrict__ w1, const float* __restrict__ b1,
    const float* __restrict__ w2, const float* __restrict__ b2,
    const float* __restrict__ w3, const float* __restrict__ b3,
    float* __restrict__ sum_x, float* __restrict__ deg, int E)
{
    __shared__ __align__(16) float w1t[64 * 84];   // K=77 pad 80, stride 84
    __shared__ __align__(16) float w2t[64 * 68];
    __shared__ __align__(16) float w3t[64 * 68];
    __shared__ float b1s[64], b2s[64], b3s[64];
    __shared__ __align__(16) float in_s[WPB][EPW][80];
    __shared__ __align__(16) float act_s[WPB][2][EPW][64];

    int tid = threadIdx.x;
    for (int idx = tid; idx < 77 * 64; idx += BLOCK) { int k = idx >> 6, j = idx & 63; w1t[j * 84 + k] = w1[idx]; }
    for (int idx = tid; idx < 3 * 64; idx += BLOCK) { int j = idx / 3, p = idx % 3; w1t[j * 84 + 77 + p] = 0.f; }
    for (int idx = tid; idx < 64 * 64; idx += BLOCK) { int k = idx >> 6, j = idx & 63; w2t[j * 68 + k] = w2[idx]; w3t[j * 68 + k] = w3[idx]; }
    if (tid < 64) { b1s[tid] = b1[tid]; b2s[tid] = b2[tid]; b3s[tid] = b3[tid]; }
    __syncthreads();

    int wid = tid >> 6, lane = tid & 63;
    int gw = blockIdx.x * WPB + wid;
    int GW = gridDim.x * WPB;
    int tot_groups = (E + EPW - 1) / EPW;
    int iters = (tot_groups + GW - 1) / GW;

    for (int it = 0; it < iters; ++it) {
        int e0 = (it * GW + gw) * EPW;
        int dreg[EPW];
        #pragma unroll
        for (int ei = 0; ei < EPW; ++ei) {
            int e = e0 + ei;
            if (e < E) {
                int s = src[e]; int d = dst[e]; dreg[ei] = d;
                in_s[wid][ei][13 + lane] = h[s * 64 + lane];
                if (lane < 2)       in_s[wid][ei][lane] = pos_state[s * 2 + lane];
                else if (lane < 4)  in_s[wid][ei][lane] = pos_state[d * 2 + lane - 2];
                else if (lane == 4) in_s[wid][ei][4]    = dis[e];
                else if (lane < 13) in_s[wid][ei][lane] = x[s * 8 + lane - 5];
                if (lane >= 61)     in_s[wid][ei][16 + lane] = 0.f;   // pad 77..79
            }
        }
        __syncthreads();

        // layer 1 (K=80 padded)
        float acc[EPW];
        #pragma unroll
        for (int ei = 0; ei < EPW; ++ei) acc[ei] = b1s[lane];
        for (int k = 0; k < 80; k += 4) {
            float4 w = *(const float4*)&w1t[lane * 84 + k];
            #pragma unroll
            for (int ei = 0; ei < EPW; ++ei) {
                float4 a = *(const float4*)&in_s[wid][ei][k];
                acc[ei] += w.x * a.x + w.y * a.y + w.z * a.z + w.w * a.w;
            }
        }
        #pragma unroll
        for (int ei = 0; ei < EPW; ++ei) act_s[wid][0][ei][lane] = tanh_fast(acc[ei]);
        __syncthreads();

        // layer 2
        #pragma unroll
        for (int ei = 0; ei < EPW; ++ei) acc[ei] = b2s[lane];
        for (int k = 0; k < 64; k += 4) {
            float4 w = *(const float4*)&w2t[lane * 68 + k];
            #pragma unroll
            for (int ei = 0; ei < EPW; ++ei) {
                float4 a = *(const float4*)&act_s[wid][0][ei][k];
                acc[ei] += w.x * a.x + w.y * a.y + w.z * a.z + w.w * a.w;
            }
        }
        #pragma unroll
        for (int ei = 0; ei < EPW; ++ei) act_s[wid][1][ei][lane] = tanh_fast(acc[ei]);
        __syncthreads();

        // layer 3 + scatter
        #pragma unroll
        for (int ei = 0; ei < EPW; ++ei) acc[ei] = b3s[lane];
        for (int k = 0; k < 64; k += 4) {
            float4 w = *(const float4*)&w3t[lane * 68 + k];
            #pragma unroll
            for (int ei = 0; ei < EPW; ++ei) {
                float4 a = *(const float4*)&act_s[wid][1][ei][k];
                acc[ei] += w.x * a.x + w.y * a.y + w.z * a.z + w.w * a.w;
            }
        }
        #pragma unroll
        for (int ei = 0; ei < EPW; ++ei) {
            if (e0 + ei < E) {
                atomicAdd(&sum_x[dreg[ei] * 64 + lane], acc[ei]);
                if (lane == 0) atomicAdd(&deg[dreg[ei]], 1.0f);
            }
        }
        __syncthreads();
    }
}

// ---------------------------------------------------------------------------
// node update MLP: in[202] = [pos_state(2), h(64), sum_u(64), mean_x(64), x(8)]
// layer1 weights read from global (L2-resident), layers 2/3 from LDS.
// ---------------------------------------------------------------------------
__global__ __launch_bounds__(BLOCK) void upd_kernel(
    const float* __restrict__ pos_state, const float* __restrict__ h,
    const float* __restrict__ x,
    const float* __restrict__ sum_u, const float* __restrict__ sum_x,
    const float* __restrict__ deg,
    const float* __restrict__ w1, const float* __restrict__ b1,
    const float* __restrict__ w2, const float* __restrict__ b2,
    const float* __restrict__ w3, const float* __restrict__ b3,
    float* __restrict__ out, int NS)
{
    __shared__ __align__(16) float w2t[64 * 68];
    __shared__ __align__(16) float w3t[64 * 68];
    __shared__ float b1s[64], b2s[64], b3s[64];
    __shared__ __align__(16) float in_s[WPB][EPW][204];
    __shared__ __align__(16) float act_s[WPB][2][EPW][64];

    int tid = threadIdx.x;
    for (int idx = tid; idx < 64 * 64; idx += BLOCK) { int k = idx >> 6, j = idx & 63; w2t[j * 68 + k] = w2[idx]; w3t[j * 68 + k] = w3[idx]; }
    if (tid < 64) { b1s[tid] = b1[tid]; b2s[tid] = b2[tid]; b3s[tid] = b3[tid]; }
    __syncthreads();

    int wid = tid >> 6, lane = tid & 63;
    int gw = blockIdx.x * WPB + wid;
    int GW = gridDim.x * WPB;
    int tot_groups = (NS + EPW - 1) / EPW;
    int iters = (tot_groups + GW - 1) / GW;

    for (int it = 0; it < iters; ++it) {
        int n0 = (it * GW + gw) * EPW;
        #pragma unroll
        for (int ei = 0; ei < EPW; ++ei) {
            int n = n0 + ei;
            if (n < NS) {
                float rd = 1.0f / fmaxf(deg[n], 1.0f);
                in_s[wid][ei][2 + lane]   = h[n * 64 + lane];
                in_s[wid][ei][66 + lane]  = sum_u[n * 64 + lane];
                in_s[wid][ei][130 + lane] = sum_x[n * 64 + lane] * rd;
                if (lane < 2) in_s[wid][ei][lane] = pos_state[n * 2 + lane];
                if (lane < 8) in_s[wid][ei][194 + lane] = x[n * 8 + lane];
            }
        }
        __syncthreads();

        // layer 1 (K=202), w1 from global: w1[k*64+lane] coalesced, L2/L1-resident
        float acc[EPW];
        #pragma unroll
        for (int ei = 0; ei < EPW; ++ei) acc[ei] = b1s[lane];
        for (int k = 0; k < 200; k += 4) {
            float w0 = w1[(k + 0) * 64 + lane];
            float wv1 = w1[(k + 1) * 64 + lane];
            float wv2 = w1[(k + 2) * 64 + lane];
            float wv3 = w1[(k + 3) * 64 + lane];
            #pragma unroll
            for (int ei = 0; ei < EPW; ++ei) {
                float4 a = *(const float4*)&in_s[wid][ei][k];
                acc[ei] += w0 * a.x + wv1 * a.y + wv2 * a.z + wv3 * a.w;
            }
        }
        for (int k = 200; k < 202; ++k) {
            float wv = w1[k * 64 + lane];
            #pragma unroll
            for (int ei = 0; ei < EPW; ++ei) acc[ei] += wv * in_s[wid][ei][k];
        }
        #pragma unroll
        for (int ei = 0; ei < EPW; ++ei) act_s[wid][0][ei][lane] = tanh_fast(acc[ei]);
        __syncthreads();

        // layer 2
        #pragma unroll
        for (int ei = 0; ei < EPW; ++ei) acc[ei] = b2s[lane];
        for (int k = 0; k < 64; k += 4) {
            float4 w = *(const float4*)&w2t[lane * 68 + k];
            #pragma unroll
            for (int ei = 0; ei < EPW; ++ei) {
                float4 a = *(const float4*)&act_s[wid][0][ei][k];
                acc[ei] += w.x * a.x + w.y * a.y + w.z * a.z + w.w * a.w;
            }
        }
        #pragma unroll
        for (int ei = 0; ei < EPW; ++ei) act_s[wid][1][ei][lane] = tanh_fast(acc[ei]);
        __syncthreads();

        // layer 3 -> out
        #pragma unroll
        for (int ei = 0; ei < EPW; ++ei) acc[ei] = b3s[lane];
        for (int k = 0; k < 64; k += 4) {
            float4 w = *(const float4*)&w3t[lane * 68 + k];
            #pragma unroll
            for (int ei = 0; ei < EPW; ++ei) {
                float4 a = *(const float4*)&act_s[wid][1][ei][k];
                acc[ei] += w.x * a.x + w.y * a.y + w.z * a.z + w.w * a.w;
            }
        }
        #pragma unroll
        for (int ei = 0; ei < EPW; ++ei) {
            int n = n0 + ei;
            if (n < NS) out[n * 64 + lane] = acc[ei];
        }
        __syncthreads();
    }
}

extern "C" void kernel_launch(void* const* d_in, const int* in_sizes, int n_in,
                              void* d_out, int out_size, void* d_ws, size_t ws_size,
                              hipStream_t stream) {
    const float* pos_state  = (const float*)d_in[0];
    const float* pos_action = (const float*)d_in[1];
    const float* h          = (const float*)d_in[2];
    const float* x          = (const float*)d_in[3];
    const float* u          = (const float*)d_in[4];
    const int*   a2s_src    = (const int*)d_in[5];
    const int*   a2s_dst    = (const int*)d_in[6];
    const float* a2s_dis    = (const float*)d_in[7];
    const int*   s2s_src    = (const int*)d_in[8];
    const int*   s2s_dst    = (const int*)d_in[9];
    const float* s2s_dis    = (const float*)d_in[10];
    const float* u2h_w1 = (const float*)d_in[11]; const float* u2h_b1 = (const float*)d_in[12];
    const float* u2h_w2 = (const float*)d_in[13]; const float* u2h_b2 = (const float*)d_in[14];
    const float* u2h_w3 = (const float*)d_in[15]; const float* u2h_b3 = (const float*)d_in[16];
    const float* x2h_w1 = (const float*)d_in[17]; const float* x2h_b1 = (const float*)d_in[18];
    const float* x2h_w2 = (const float*)d_in[19]; const float* x2h_b2 = (const float*)d_in[20];
    const float* x2h_w3 = (const float*)d_in[21]; const float* x2h_b3 = (const float*)d_in[22];
    const float* upd_w1 = (const float*)d_in[23]; const float* upd_b1 = (const float*)d_in[24];
    const float* upd_w2 = (const float*)d_in[25]; const float* upd_b2 = (const float*)d_in[26];
    const float* upd_w3 = (const float*)d_in[27]; const float* upd_b3 = (const float*)d_in[28];

    int NS = in_sizes[0] / 2;
    int EA = in_sizes[5];
    int ES = in_sizes[8];

    float* ws    = (float*)d_ws;
    float* sum_u = ws;                         // NS*64
    float* sum_x = ws + (size_t)NS * 64;       // NS*64
    float* deg   = ws + (size_t)NS * 128;      // NS

    hipMemsetAsync(d_ws, 0, ((size_t)NS * 128 + NS) * sizeof(float), stream);

    a2s_kernel<<<1024, BLOCK, 0, stream>>>(pos_state, pos_action, u,
                                           a2s_src, a2s_dst, a2s_dis,
                                           u2h_w1, u2h_b1, u2h_w2, u2h_b2, u2h_w3, u2h_b3,
                                           sum_u, EA);
    s2s_kernel<<<2048, BLOCK, 0, stream>>>(pos_state, x, h,
                                           s2s_src, s2s_dst, s2s_dis,
                                           x2h_w1, x2h_b1, x2h_w2, x2h_b2, x2h_w3, x2h_b3,
                                           sum_x, deg, ES);
    upd_kernel<<<512, BLOCK, 0, stream>>>(pos_state, h, x, sum_u, sum_x, deg,
                                          upd_w1, upd_b1, upd_w2, upd_b2, upd_w3, upd_b3,
                                          (float*)d_out, NS);
}

// Round 2
// 591.613 us; speedup vs baseline: 5.1900x; 5.1900x over previous
//
#include <hip/hip_runtime.h>
#include <hip/hip_bf16.h>

// R2: MFMA rewrite. All three stages as bf16 16x16x32 MFMA GEMMs.
// - B (weights) in LDS in fragment order (lane*16B contiguous -> conflict-free ds_read_b128)
// - A gathered direct from global (L2-resident), converted fp32->bf16 RNE in regs
// - tanh between layers via C-layout -> LDS A-frag-layout round trip (wave-private, no barriers)
// - scatter via unsafeAtomicAdd (HW global_atomic_add_f32, not CAS)

typedef __attribute__((ext_vector_type(8))) short short8;
typedef __attribute__((ext_vector_type(4))) float f32x4;

__device__ __forceinline__ unsigned short f2bf(float f) {
    unsigned u = __float_as_uint(f);
    u += 0x7fffu + ((u >> 16) & 1u);   // RNE (NaN-free data)
    return (unsigned short)(u >> 16);
}

__device__ __forceinline__ float tanh_fast(float xv) {
    float t = __builtin_amdgcn_exp2f(xv * 2.8853900817779268f); // 2*log2(e)
    return 1.0f - 2.0f * __builtin_amdgcn_rcpf(t + 1.0f);
}

union Frag { short8 v; unsigned short u[8]; };

// Build B-operand fragments into LDS.
// frag(c,nt) at dst[((c*4+nt)*64 + lane)*8 + j] = w[k*64+n], n = nt*16+(lane&15),
// k = c*32 + (lane>>4)*8 + j, zero-padded for k>=K. w is row-major [K][64].
__device__ void build_B(const float* __restrict__ w, int K, int nchunks,
                        unsigned short* dst, int tid) {
    int total = nchunks * 4 * 64;
    for (int f = tid; f < total; f += 256) {
        int lv = f & 63;
        int nt = (f >> 6) & 3;
        int c  = f >> 8;
        int n  = nt * 16 + (lv & 15);
        int kb = c * 32 + ((lv >> 4) << 3);
        unsigned short* o = dst + f * 8;
        #pragma unroll
        for (int j = 0; j < 8; ++j) {
            int k = kb + j;
            o[j] = (k < K) ? f2bf(w[k * 64 + n]) : (unsigned short)0;
        }
    }
}

#define MFMA_BF16 __builtin_amdgcn_mfma_f32_16x16x32_bf16

// ---------------------------------------------------------------------------
// s2s: in[77] = [ps[s](2), ps[d](2), dis(1), x[s](8), h[s](64)], 3-chunk K.
// M=32 edges/wave (2 m-tiles). Scatter sum into sum_x, count deg.
// ---------------------------------------------------------------------------
__global__ __launch_bounds__(256, 3) void s2s_mfma(
    const float* __restrict__ ps, const float* __restrict__ x,
    const float* __restrict__ h,
    const int* __restrict__ src, const int* __restrict__ dst,
    const float* __restrict__ dis,
    const float* __restrict__ w1, const float* __restrict__ b1,
    const float* __restrict__ w2, const float* __restrict__ b2,
    const float* __restrict__ w3, const float* __restrict__ b3,
    float* __restrict__ sum_x, float* __restrict__ deg, int E)
{
    __shared__ __align__(16) unsigned short B1[3*4*64*8];
    __shared__ __align__(16) unsigned short B2[2*4*64*8];
    __shared__ __align__(16) unsigned short B3[2*4*64*8];
    __shared__ __align__(16) unsigned short Z[4][2*2*512]; // [wave][(c*2+mt)*512]

    int tid = threadIdx.x;
    build_B(w1, 77, 3, B1, tid);
    build_B(w2, 64, 2, B2, tid);
    build_B(w3, 64, 2, B3, tid);
    __syncthreads();

    int wid = tid >> 6, lane = tid & 63;
    int m16 = lane & 15, q = lane >> 4;
    unsigned short* Zw = Z[wid];

    float bb1[4], bb2[4], bb3[4];
    #pragma unroll
    for (int nt = 0; nt < 4; ++nt) {
        bb1[nt] = b1[nt*16 + m16];
        bb2[nt] = b2[nt*16 + m16];
        bb3[nt] = b3[nt*16 + m16];
    }

    int T = E >> 5;   // E divisible by 32
    int gw = blockIdx.x * 4 + wid, GW = gridDim.x * 4;

    for (int t = gw; t < T; t += GW) {
        int e0 = t * 32;
        int sA = src[e0 + m16],      dA = dst[e0 + m16];
        int sB = src[e0 + 16 + m16], dB = dst[e0 + 16 + m16];
        float dzA = dis[e0 + m16], dzB = dis[e0 + 16 + m16];
        int dsc[2][4];
        #pragma unroll
        for (int mt = 0; mt < 2; ++mt)
            #pragma unroll
            for (int r = 0; r < 4; ++r)
                dsc[mt][r] = dst[e0 + mt*16 + (q<<2) + r];

        f32x4 acc[2][4];
        #pragma unroll
        for (int mt = 0; mt < 2; ++mt)
            #pragma unroll
            for (int nt = 0; nt < 4; ++nt)
                acc[mt][nt] = (f32x4){0.f, 0.f, 0.f, 0.f};

        // ---- layer 1 (K=77 -> 3 chunks of 32)
        #pragma unroll
        for (int c = 0; c < 3; ++c) {
            Frag A[2];
            #pragma unroll
            for (int mt = 0; mt < 2; ++mt) {
                int s = mt ? sB : sA;
                int d = mt ? dB : dA;
                float dz = mt ? dzB : dzA;
                #pragma unroll
                for (int j = 0; j < 8; ++j) {
                    int k = c*32 + q*8 + j;
                    float v;
                    if (k >= 77)      v = 0.f;
                    else if (k >= 13) v = h[s*64 + (k-13)];
                    else if (k < 2)   v = ps[s*2 + k];
                    else if (k < 4)   v = ps[d*2 + (k-2)];
                    else if (k == 4)  v = dz;
                    else              v = x[s*8 + (k-5)];
                    A[mt].u[j] = f2bf(v);
                }
            }
            #pragma unroll
            for (int nt = 0; nt < 4; ++nt) {
                short8 bf = *(const short8*)(B1 + ((c*4+nt)*64 + lane)*8);
                acc[0][nt] = MFMA_BF16(A[0].v, bf, acc[0][nt], 0, 0, 0);
                acc[1][nt] = MFMA_BF16(A[1].v, bf, acc[1][nt], 0, 0, 0);
            }
        }

        // tanh(+bias) -> Z in A-frag layout for layer 2
        #pragma unroll
        for (int mt = 0; mt < 2; ++mt)
            #pragma unroll
            for (int nt = 0; nt < 4; ++nt) {
                int c  = nt >> 1;
                int qp = ((nt & 1) << 1) + (m16 >> 3);
                #pragma unroll
                for (int r = 0; r < 4; ++r) {
                    float v = tanh_fast(acc[mt][nt][r] + bb1[nt]);
                    int lp = (q << 2) + r + (qp << 4);
                    Zw[(c*2 + mt)*512 + lp*8 + (m16 & 7)] = f2bf(v);
                }
            }

        // ---- layer 2
        Frag A2[2][2];
        #pragma unroll
        for (int mt = 0; mt < 2; ++mt)
            #pragma unroll
            for (int c = 0; c < 2; ++c)
                A2[mt][c].v = *(const short8*)(Zw + (c*2 + mt)*512 + lane*8);
        #pragma unroll
        for (int mt = 0; mt < 2; ++mt)
            #pragma unroll
            for (int nt = 0; nt < 4; ++nt)
                acc[mt][nt] = (f32x4){0.f, 0.f, 0.f, 0.f};
        #pragma unroll
        for (int c = 0; c < 2; ++c)
            #pragma unroll
            for (int nt = 0; nt < 4; ++nt) {
                short8 bf = *(const short8*)(B2 + ((c*4+nt)*64 + lane)*8);
                acc[0][nt] = MFMA_BF16(A2[0][c].v, bf, acc[0][nt], 0, 0, 0);
                acc[1][nt] = MFMA_BF16(A2[1][c].v, bf, acc[1][nt], 0, 0, 0);
            }

        // tanh(+bias) -> Z (reuse; per-wave DS ops are in-order, reads above precede)
        #pragma unroll
        for (int mt = 0; mt < 2; ++mt)
            #pragma unroll
            for (int nt = 0; nt < 4; ++nt) {
                int c  = nt >> 1;
                int qp = ((nt & 1) << 1) + (m16 >> 3);
                #pragma unroll
                for (int r = 0; r < 4; ++r) {
                    float v = tanh_fast(acc[mt][nt][r] + bb2[nt]);
                    int lp = (q << 2) + r + (qp << 4);
                    Zw[(c*2 + mt)*512 + lp*8 + (m16 & 7)] = f2bf(v);
                }
            }

        // ---- layer 3
        Frag A3[2][2];
        #pragma unroll
        for (int mt = 0; mt < 2; ++mt)
            #pragma unroll
            for (int c = 0; c < 2; ++c)
                A3[mt][c].v = *(const short8*)(Zw + (c*2 + mt)*512 + lane*8);
        #pragma unroll
        for (int mt = 0; mt < 2; ++mt)
            #pragma unroll
            for (int nt = 0; nt < 4; ++nt)
                acc[mt][nt] = (f32x4){0.f, 0.f, 0.f, 0.f};
        #pragma unroll
        for (int c = 0; c < 2; ++c)
            #pragma unroll
            for (int nt = 0; nt < 4; ++nt) {
                short8 bf = *(const short8*)(B3 + ((c*4+nt)*64 + lane)*8);
                acc[0][nt] = MFMA_BF16(A3[0][c].v, bf, acc[0][nt], 0, 0, 0);
                acc[1][nt] = MFMA_BF16(A3[1][c].v, bf, acc[1][nt], 0, 0, 0);
            }

        // scatter (+bias): C-layout lane holds (row=q*4+r, col=nt*16+m16)
        #pragma unroll
        for (int mt = 0; mt < 2; ++mt)
            #pragma unroll
            for (int nt = 0; nt < 4; ++nt)
                #pragma unroll
                for (int r = 0; r < 4; ++r) {
                    float v = acc[mt][nt][r] + bb3[nt];
                    unsafeAtomicAdd(&sum_x[(size_t)dsc[mt][r]*64 + nt*16 + m16], v);
                }
        if (lane < 32) unsafeAtomicAdd(&deg[dst[e0 + lane]], 1.0f);
    }
}

// ---------------------------------------------------------------------------
// a2s: in[13] = [pa[s](2), ps[d](2), dis(1), u[s](8)], 1-chunk K. Scatter sum_u.
// ---------------------------------------------------------------------------
__global__ __launch_bounds__(256, 3) void a2s_mfma(
    const float* __restrict__ ps, const float* __restrict__ pa,
    const float* __restrict__ u,
    const int* __restrict__ src, const int* __restrict__ dst,
    const float* __restrict__ dis,
    const float* __restrict__ w1, const float* __restrict__ b1,
    const float* __restrict__ w2, const float* __restrict__ b2,
    const float* __restrict__ w3, const float* __restrict__ b3,
    float* __restrict__ sum_u, int E)
{
    __shared__ __align__(16) unsigned short B1[1*4*64*8];
    __shared__ __align__(16) unsigned short B2[2*4*64*8];
    __shared__ __align__(16) unsigned short B3[2*4*64*8];
    __shared__ __align__(16) unsigned short Z[4][2*2*512];

    int tid = threadIdx.x;
    build_B(w1, 13, 1, B1, tid);
    build_B(w2, 64, 2, B2, tid);
    build_B(w3, 64, 2, B3, tid);
    __syncthreads();

    int wid = tid >> 6, lane = tid & 63;
    int m16 = lane & 15, q = lane >> 4;
    unsigned short* Zw = Z[wid];

    float bb1[4], bb2[4], bb3[4];
    #pragma unroll
    for (int nt = 0; nt < 4; ++nt) {
        bb1[nt] = b1[nt*16 + m16];
        bb2[nt] = b2[nt*16 + m16];
        bb3[nt] = b3[nt*16 + m16];
    }

    int T = E >> 5;
    int gw = blockIdx.x * 4 + wid, GW = gridDim.x * 4;

    for (int t = gw; t < T; t += GW) {
        int e0 = t * 32;
        int sA = src[e0 + m16],      dA = dst[e0 + m16];
        int sB = src[e0 + 16 + m16], dB = dst[e0 + 16 + m16];
        float dzA = dis[e0 + m16], dzB = dis[e0 + 16 + m16];
        int dsc[2][4];
        #pragma unroll
        for (int mt = 0; mt < 2; ++mt)
            #pragma unroll
            for (int r = 0; r < 4; ++r)
                dsc[mt][r] = dst[e0 + mt*16 + (q<<2) + r];

        f32x4 acc[2][4];
        #pragma unroll
        for (int mt = 0; mt < 2; ++mt)
            #pragma unroll
            for (int nt = 0; nt < 4; ++nt)
                acc[mt][nt] = (f32x4){0.f, 0.f, 0.f, 0.f};

        // layer 1 (single chunk, K=13 zero-padded to 32)
        {
            Frag A[2];
            #pragma unroll
            for (int mt = 0; mt < 2; ++mt) {
                int s = mt ? sB : sA;
                int d = mt ? dB : dA;
                float dz = mt ? dzB : dzA;
                #pragma unroll
                for (int j = 0; j < 8; ++j) {
                    int k = q*8 + j;
                    float v;
                    if (k >= 13)     v = 0.f;
                    else if (k < 2)  v = pa[s*2 + k];
                    else if (k < 4)  v = ps[d*2 + (k-2)];
                    else if (k == 4) v = dz;
                    else             v = u[s*8 + (k-5)];
                    A[mt].u[j] = f2bf(v);
                }
            }
            #pragma unroll
            for (int nt = 0; nt < 4; ++nt) {
                short8 bf = *(const short8*)(B1 + (nt*64 + lane)*8);
                acc[0][nt] = MFMA_BF16(A[0].v, bf, acc[0][nt], 0, 0, 0);
                acc[1][nt] = MFMA_BF16(A[1].v, bf, acc[1][nt], 0, 0, 0);
            }
        }

        #pragma unroll
        for (int mt = 0; mt < 2; ++mt)
            #pragma unroll
            for (int nt = 0; nt < 4; ++nt) {
                int c  = nt >> 1;
                int qp = ((nt & 1) << 1) + (m16 >> 3);
                #pragma unroll
                for (int r = 0; r < 4; ++r) {
                    float v = tanh_fast(acc[mt][nt][r] + bb1[nt]);
                    int lp = (q << 2) + r + (qp << 4);
                    Zw[(c*2 + mt)*512 + lp*8 + (m16 & 7)] = f2bf(v);
                }
            }

        Frag A2[2][2];
        #pragma unroll
        for (int mt = 0; mt < 2; ++mt)
            #pragma unroll
            for (int c = 0; c < 2; ++c)
                A2[mt][c].v = *(const short8*)(Zw + (c*2 + mt)*512 + lane*8);
        #pragma unroll
        for (int mt = 0; mt < 2; ++mt)
            #pragma unroll
            for (int nt = 0; nt < 4; ++nt)
                acc[mt][nt] = (f32x4){0.f, 0.f, 0.f, 0.f};
        #pragma unroll
        for (int c = 0; c < 2; ++c)
            #pragma unroll
            for (int nt = 0; nt < 4; ++nt) {
                short8 bf = *(const short8*)(B2 + ((c*4+nt)*64 + lane)*8);
                acc[0][nt] = MFMA_BF16(A2[0][c].v, bf, acc[0][nt], 0, 0, 0);
                acc[1][nt] = MFMA_BF16(A2[1][c].v, bf, acc[1][nt], 0, 0, 0);
            }

        #pragma unroll
        for (int mt = 0; mt < 2; ++mt)
            #pragma unroll
            for (int nt = 0; nt < 4; ++nt) {
                int c  = nt >> 1;
                int qp = ((nt & 1) << 1) + (m16 >> 3);
                #pragma unroll
                for (int r = 0; r < 4; ++r) {
                    float v = tanh_fast(acc[mt][nt][r] + bb2[nt]);
                    int lp = (q << 2) + r + (qp << 4);
                    Zw[(c*2 + mt)*512 + lp*8 + (m16 & 7)] = f2bf(v);
                }
            }

        Frag A3[2][2];
        #pragma unroll
        for (int mt = 0; mt < 2; ++mt)
            #pragma unroll
            for (int c = 0; c < 2; ++c)
                A3[mt][c].v = *(const short8*)(Zw + (c*2 + mt)*512 + lane*8);
        #pragma unroll
        for (int mt = 0; mt < 2; ++mt)
            #pragma unroll
            for (int nt = 0; nt < 4; ++nt)
                acc[mt][nt] = (f32x4){0.f, 0.f, 0.f, 0.f};
        #pragma unroll
        for (int c = 0; c < 2; ++c)
            #pragma unroll
            for (int nt = 0; nt < 4; ++nt) {
                short8 bf = *(const short8*)(B3 + ((c*4+nt)*64 + lane)*8);
                acc[0][nt] = MFMA_BF16(A3[0][c].v, bf, acc[0][nt], 0, 0, 0);
                acc[1][nt] = MFMA_BF16(A3[1][c].v, bf, acc[1][nt], 0, 0, 0);
            }

        #pragma unroll
        for (int mt = 0; mt < 2; ++mt)
            #pragma unroll
            for (int nt = 0; nt < 4; ++nt)
                #pragma unroll
                for (int r = 0; r < 4; ++r) {
                    float v = acc[mt][nt][r] + bb3[nt];
                    unsafeAtomicAdd(&sum_u[(size_t)dsc[mt][r]*64 + nt*16 + m16], v);
                }
    }
}

// ---------------------------------------------------------------------------
// upd: in[202] = [ps(2), h(64), sum_u(64), sum_x*rdeg(64), x(8)], 7-chunk K.
// M=16 nodes/wave. Direct store to out.
// ---------------------------------------------------------------------------
__global__ __launch_bounds__(256, 3) void upd_mfma(
    const float* __restrict__ ps, const float* __restrict__ h,
    const float* __restrict__ x,
    const float* __restrict__ su, const float* __restrict__ sx,
    const float* __restrict__ deg,
    const float* __restrict__ w1, const float* __restrict__ b1,
    const float* __restrict__ w2, const float* __restrict__ b2,
    const float* __restrict__ w3, const float* __restrict__ b3,
    float* __restrict__ out, int NS)
{
    __shared__ __align__(16) unsigned short B1[7*4*64*8];
    __shared__ __align__(16) unsigned short B2[2*4*64*8];
    __shared__ __align__(16) unsigned short B3[2*4*64*8];
    __shared__ __align__(16) unsigned short Z[4][2*512];

    int tid = threadIdx.x;
    build_B(w1, 202, 7, B1, tid);
    build_B(w2, 64, 2, B2, tid);
    build_B(w3, 64, 2, B3, tid);
    __syncthreads();

    int wid = tid >> 6, lane = tid & 63;
    int m16 = lane & 15, q = lane >> 4;
    unsigned short* Zw = Z[wid];

    float bb1[4], bb2[4], bb3[4];
    #pragma unroll
    for (int nt = 0; nt < 4; ++nt) {
        bb1[nt] = b1[nt*16 + m16];
        bb2[nt] = b2[nt*16 + m16];
        bb3[nt] = b3[nt*16 + m16];
    }

    int T = NS >> 4;   // NS divisible by 16
    int gw = blockIdx.x * 4 + wid, GW = gridDim.x * 4;

    for (int t = gw; t < T; t += GW) {
        int n0 = t * 16;
        int n = n0 + m16;          // gather row for this lane's A fragments
        float rd = 1.0f / fmaxf(deg[n], 1.0f);

        f32x4 acc[4];
        #pragma unroll
        for (int nt = 0; nt < 4; ++nt) acc[nt] = (f32x4){0.f, 0.f, 0.f, 0.f};

        // layer 1 (K=202 -> 7 chunks)
        #pragma unroll
        for (int c = 0; c < 7; ++c) {
            Frag A;
            #pragma unroll
            for (int j = 0; j < 8; ++j) {
                int k = c*32 + q*8 + j;
                float v;
                if (k >= 202)      v = 0.f;
                else if (k < 2)    v = ps[n*2 + k];
                else if (k < 66)   v = h[n*64 + (k-2)];
                else if (k < 130)  v = su[n*64 + (k-66)];
                else if (k < 194)  v = sx[n*64 + (k-130)] * rd;
                else               v = x[n*8 + (k-194)];
                A.u[j] = f2bf(v);
            }
            #pragma unroll
            for (int nt = 0; nt < 4; ++nt) {
                short8 bf = *(const short8*)(B1 + ((c*4+nt)*64 + lane)*8);
                acc[nt] = MFMA_BF16(A.v, bf, acc[nt], 0, 0, 0);
            }
        }

        #pragma unroll
        for (int nt = 0; nt < 4; ++nt) {
            int c  = nt >> 1;
            int qp = ((nt & 1) << 1) + (m16 >> 3);
            #pragma unroll
            for (int r = 0; r < 4; ++r) {
                float v = tanh_fast(acc[nt][r] + bb1[nt]);
                int lp = (q << 2) + r + (qp << 4);
                Zw[c*512 + lp*8 + (m16 & 7)] = f2bf(v);
            }
        }

        Frag A2[2];
        #pragma unroll
        for (int c = 0; c < 2; ++c)
            A2[c].v = *(const short8*)(Zw + c*512 + lane*8);
        #pragma unroll
        for (int nt = 0; nt < 4; ++nt) acc[nt] = (f32x4){0.f, 0.f, 0.f, 0.f};
        #pragma unroll
        for (int c = 0; c < 2; ++c)
            #pragma unroll
            for (int nt = 0; nt < 4; ++nt) {
                short8 bf = *(const short8*)(B2 + ((c*4+nt)*64 + lane)*8);
                acc[nt] = MFMA_BF16(A2[c].v, bf, acc[nt], 0, 0, 0);
            }

        #pragma unroll
        for (int nt = 0; nt < 4; ++nt) {
            int c  = nt >> 1;
            int qp = ((nt & 1) << 1) + (m16 >> 3);
            #pragma unroll
            for (int r = 0; r < 4; ++r) {
                float v = tanh_fast(acc[nt][r] + bb2[nt]);
                int lp = (q << 2) + r + (qp << 4);
                Zw[c*512 + lp*8 + (m16 & 7)] = f2bf(v);
            }
        }

        Frag A3[2];
        #pragma unroll
        for (int c = 0; c < 2; ++c)
            A3[c].v = *(const short8*)(Zw + c*512 + lane*8);
        #pragma unroll
        for (int nt = 0; nt < 4; ++nt) acc[nt] = (f32x4){0.f, 0.f, 0.f, 0.f};
        #pragma unroll
        for (int c = 0; c < 2; ++c)
            #pragma unroll
            for (int nt = 0; nt < 4; ++nt) {
                short8 bf = *(const short8*)(B3 + ((c*4+nt)*64 + lane)*8);
                acc[nt] = MFMA_BF16(A3[c].v, bf, acc[nt], 0, 0, 0);
            }

        // store (+bias): lane holds (row=q*4+r, col=nt*16+m16)
        #pragma unroll
        for (int nt = 0; nt < 4; ++nt)
            #pragma unroll
            for (int r = 0; r < 4; ++r) {
                int row = (q << 2) + r;
                out[(size_t)(n0 + row)*64 + nt*16 + m16] = acc[nt][r] + bb3[nt];
            }
    }
}

extern "C" void kernel_launch(void* const* d_in, const int* in_sizes, int n_in,
                              void* d_out, int out_size, void* d_ws, size_t ws_size,
                              hipStream_t stream) {
    const float* pos_state  = (const float*)d_in[0];
    const float* pos_action = (const float*)d_in[1];
    const float* h          = (const float*)d_in[2];
    const float* x          = (const float*)d_in[3];
    const float* u          = (const float*)d_in[4];
    const int*   a2s_src    = (const int*)d_in[5];
    const int*   a2s_dst    = (const int*)d_in[6];
    const float* a2s_dis    = (const float*)d_in[7];
    const int*   s2s_src    = (const int*)d_in[8];
    const int*   s2s_dst    = (const int*)d_in[9];
    const float* s2s_dis    = (const float*)d_in[10];
    const float* u2h_w1 = (const float*)d_in[11]; const float* u2h_b1 = (const float*)d_in[12];
    const float* u2h_w2 = (const float*)d_in[13]; const float* u2h_b2 = (const float*)d_in[14];
    const float* u2h_w3 = (const float*)d_in[15]; const float* u2h_b3 = (const float*)d_in[16];
    const float* x2h_w1 = (const float*)d_in[17]; const float* x2h_b1 = (const float*)d_in[18];
    const float* x2h_w2 = (const float*)d_in[19]; const float* x2h_b2 = (const float*)d_in[20];
    const float* x2h_w3 = (const float*)d_in[21]; const float* x2h_b3 = (const float*)d_in[22];
    const float* upd_w1 = (const float*)d_in[23]; const float* upd_b1 = (const float*)d_in[24];
    const float* upd_w2 = (const float*)d_in[25]; const float* upd_b2 = (const float*)d_in[26];
    const float* upd_w3 = (const float*)d_in[27]; const float* upd_b3 = (const float*)d_in[28];

    int NS = in_sizes[0] / 2;
    int EA = in_sizes[5];
    int ES = in_sizes[8];

    float* ws    = (float*)d_ws;
    float* sum_u = ws;                         // NS*64
    float* sum_x = ws + (size_t)NS * 64;       // NS*64
    float* deg   = ws + (size_t)NS * 128;      // NS

    hipMemsetAsync(d_ws, 0, ((size_t)NS * 128 + NS) * sizeof(float), stream);

    a2s_mfma<<<1024, 256, 0, stream>>>(pos_state, pos_action, u,
                                       a2s_src, a2s_dst, a2s_dis,
                                       u2h_w1, u2h_b1, u2h_w2, u2h_b2, u2h_w3, u2h_b3,
                                       sum_u, EA);
    s2s_mfma<<<768, 256, 0, stream>>>(pos_state, x, h,
                                      s2s_src, s2s_dst, s2s_dis,
                                      x2h_w1, x2h_b1, x2h_w2, x2h_b2, x2h_w3, x2h_b3,
                                      sum_x, deg, ES);
    upd_mfma<<<768, 256, 0, stream>>>(pos_state, h, x, sum_u, sum_x, deg,
                                      upd_w1, upd_b1, upd_w2, upd_b2, upd_w3, upd_b3,
                                      (float*)d_out, NS);
}